// Round 1
// baseline (452.192 us; speedup 1.0000x reference)
//
#include <hip/hip_runtime.h>
#include <math.h>

#define NQ   512
#define NKV  1280
#define CDIM 128

// workspace layout (float offsets)
#define OFF_WQT_SA   0         // 16384  [j=128][c=128]
#define OFF_WQT_DA   16384     // 16384
#define OFF_WKVT_SA  32768     // 32768  [j=128][c=256]
#define OFF_WKVT_DA  65536     // 32768
#define OFF_PROJT_SA 98304     // 16384  [j=128][c=128]
#define OFF_PROJT_DA 114688    // 16384
#define OFF_GATET_SA 131072    // 32768  [j=256][c=128]
#define OFF_GATET_DA 163840    // 32768
#define OFF_WDSUM    196608    // 4
#define OFF_QSA      196612    // 65536  [n=512][c=128]
#define OFF_QDA      262148    // 65536
#define OFF_KSAT     327684    // 163840 [c=128][k=1280]  (transposed)
#define OFF_VSA      491524    // 163840 [k=1280][c=128]
#define OFF_KDAT     655364    // 163840 [c=128][k=1280]
#define OFF_VDA      819204    // 163840 [k=1280][c=128]
#define OFF_OUTSA    983044    // 65536  [n=512][c=128] (pre-reinterpret)
#define OFF_OUTDA    1048580   // 65536
// total 1114116 floats = 4.25 MB

// ---------------------------------------------------------------- weights
__global__ __launch_bounds__(256) void prep_weights_kernel(
    const float* __restrict__ wq_sa, const float* __restrict__ wkv_sa,
    const float* __restrict__ proj_sa, const float* __restrict__ wq_da,
    const float* __restrict__ wkv_da, const float* __restrict__ proj_da,
    const float* __restrict__ gate_sa, const float* __restrict__ gate_da,
    const float* __restrict__ wdelta, float* __restrict__ ws)
{
  int idx = blockIdx.x * 256 + threadIdx.x;
  if (idx < 16384) {                    // all 128x128 matrices
    int j = idx >> 7, c = idx & 127;
    int s = c * 128 + j;
    ws[OFF_WQT_SA + idx]   = wq_sa[s];
    ws[OFF_WQT_DA + idx]   = wq_da[s];
    ws[OFF_PROJT_SA + idx] = proj_sa[s];
    ws[OFF_PROJT_DA + idx] = proj_da[s];
  } else if (idx < 49152) {             // kv weights (256x128)
    int i2 = idx - 16384;
    int j = i2 >> 8, c = i2 & 255;
    int s = c * 128 + j;
    ws[OFF_WKVT_SA + i2] = wkv_sa[s];
    ws[OFF_WKVT_DA + i2] = wkv_da[s];
  } else if (idx < 81920) {             // gate weights (128x256)
    int i2 = idx - 49152;
    int j = i2 >> 7, c = i2 & 127;
    int s = c * 256 + j;
    ws[OFF_GATET_SA + i2] = gate_sa[s];
    ws[OFF_GATET_DA + i2] = gate_da[s];
  } else if (idx < 81923) {             // Wdelta.sum(0)
    int t3 = idx - 81920;
    float s = 0.f;
    for (int i = 0; i < 128; ++i) s += wdelta[i * 3 + t3];
    ws[OFF_WDSUM + t3] = s;
  }
}

// ---------------------------------------------------------------- q proj
// block: 256 threads, 8 query rows. t<128 -> q_sa feature t; t>=128 -> q_da.
__global__ __launch_bounds__(256) void qproj_kernel(
    const float* __restrict__ erp, float* __restrict__ ws)
{
  __shared__ float qrows[8][CDIM];
  int n0 = blockIdx.x * 8, t = threadIdx.x;
  for (int i = t; i < 8 * CDIM; i += 256)
    qrows[i & 7][i >> 3] = erp[(i >> 3) * NQ + n0 + (i & 7)];
  __syncthreads();
  const float* w = (t < 128) ? (ws + OFF_WQT_SA) : (ws + OFF_WQT_DA);
  int c = t & 127;
  float acc[8] = {0,0,0,0,0,0,0,0};
  #pragma unroll 4
  for (int j = 0; j < CDIM; ++j) {
    float wj = w[j * 128 + c];
    #pragma unroll
    for (int r = 0; r < 8; ++r) acc[r] = fmaf(qrows[r][j], wj, acc[r]);
  }
  float* o = (t < 128) ? (ws + OFF_QSA) : (ws + OFF_QDA);
  #pragma unroll
  for (int r = 0; r < 8; ++r) o[(n0 + r) * CDIM + c] = acc[r];
}

// ---------------------------------------------------------------- kv proj
// block: 256 threads, 8 keys. t indexes the 256 output cols of Wkv^T
// (t<128: k feature t ; t>=128: v feature t-128).
__global__ __launch_bounds__(256) void kvproj_kernel(
    const float* __restrict__ ico, float* __restrict__ ws)
{
  __shared__ float irow[8][CDIM];
  int k0 = blockIdx.x * 8, t = threadIdx.x;
  for (int i = t; i < 8 * CDIM; i += 256)
    irow[i >> 7][i & 127] = ico[(k0 + (i >> 7)) * CDIM + (i & 127)];
  __syncthreads();
  const float* wsa = ws + OFF_WKVT_SA;
  const float* wda = ws + OFF_WKVT_DA;
  float acc_s[8] = {0,0,0,0,0,0,0,0};
  float acc_d[8] = {0,0,0,0,0,0,0,0};
  #pragma unroll 4
  for (int j = 0; j < CDIM; ++j) {
    float wsj = wsa[j * 256 + t];
    float wdj = wda[j * 256 + t];
    #pragma unroll
    for (int ky = 0; ky < 8; ++ky) {
      float x = irow[ky][j];
      acc_s[ky] = fmaf(x, wsj, acc_s[ky]);
      acc_d[ky] = fmaf(x, wdj, acc_d[ky]);
    }
  }
  if (t < 128) {  // k features -> transposed layout, 8 consecutive k = 2x float4
    float* ks = ws + OFF_KSAT + t * NKV + k0;
    float* kd = ws + OFF_KDAT + t * NKV + k0;
    *(float4*)(ks)     = make_float4(acc_s[0], acc_s[1], acc_s[2], acc_s[3]);
    *(float4*)(ks + 4) = make_float4(acc_s[4], acc_s[5], acc_s[6], acc_s[7]);
    *(float4*)(kd)     = make_float4(acc_d[0], acc_d[1], acc_d[2], acc_d[3]);
    *(float4*)(kd + 4) = make_float4(acc_d[4], acc_d[5], acc_d[6], acc_d[7]);
  } else {        // v features -> row-major
    int c = t - 128;
    #pragma unroll
    for (int ky = 0; ky < 8; ++ky) {
      ws[OFF_VSA + (k0 + ky) * CDIM + c] = acc_s[ky];
      ws[OFF_VDA + (k0 + ky) * CDIM + c] = acc_d[ky];
    }
  }
}

// ---------------------------------------------------------------- sa attention
// block: 256 threads, 4 query rows. scores -> softmax -> AV, all in LDS.
__global__ __launch_bounds__(256) void attn_sa_kernel(float* __restrict__ ws)
{
  __shared__ float4 qs4[CDIM];          // [j] -> rows 0..3
  __shared__ float sc[4][NKV];
  __shared__ float red[4];
  __shared__ float s_inv[4];
  int t = threadIdx.x;
  int n0 = blockIdx.x * 4;
  float* qsf = (float*)qs4;
  for (int i = t; i < 4 * CDIM; i += 256) {
    int r = i >> 7, j = i & 127;
    qsf[j * 4 + r] = ws[OFF_QSA + (n0 + r) * CDIM + j];
  }
  __syncthreads();
  const float* ksat = ws + OFF_KSAT;
  const float scale = 0.088388347648318447f;  // 128^-0.5
  #pragma unroll
  for (int ki = 0; ki < 5; ++ki) {
    int k = t + ki * 256;
    float a0 = 0.f, a1 = 0.f, a2 = 0.f, a3 = 0.f;
    #pragma unroll 4
    for (int j = 0; j < CDIM; ++j) {
      float kv = ksat[j * NKV + k];
      float4 q = qs4[j];
      a0 = fmaf(q.x, kv, a0);
      a1 = fmaf(q.y, kv, a1);
      a2 = fmaf(q.z, kv, a2);
      a3 = fmaf(q.w, kv, a3);
    }
    sc[0][k] = a0 * scale; sc[1][k] = a1 * scale;
    sc[2][k] = a2 * scale; sc[3][k] = a3 * scale;
  }
  for (int r = 0; r < 4; ++r) {
    float lm = -1e30f;
    #pragma unroll
    for (int ki = 0; ki < 5; ++ki) lm = fmaxf(lm, sc[r][t + ki * 256]);
    for (int o = 32; o > 0; o >>= 1) lm = fmaxf(lm, __shfl_down(lm, o, 64));
    __syncthreads();
    if ((t & 63) == 0) red[t >> 6] = lm;
    __syncthreads();
    float m = fmaxf(fmaxf(red[0], red[1]), fmaxf(red[2], red[3]));
    float ls = 0.f;
    #pragma unroll
    for (int ki = 0; ki < 5; ++ki) {
      int k = t + ki * 256;
      float e = __expf(sc[r][k] - m);
      sc[r][k] = e;
      ls += e;
    }
    for (int o = 32; o > 0; o >>= 1) ls += __shfl_down(ls, o, 64);
    __syncthreads();
    if ((t & 63) == 0) red[t >> 6] = ls;
    __syncthreads();
    if (t == 0) s_inv[r] = 1.0f / (red[0] + red[1] + red[2] + red[3]);
  }
  __syncthreads();
  const float* v = ws + OFF_VSA;
  int c = t & 127, rr = t >> 7;         // this thread: rows rr and rr+2
  float acc0 = 0.f, acc1 = 0.f;
  #pragma unroll 4
  for (int k = 0; k < NKV; ++k) {
    float vv = v[k * CDIM + c];
    acc0 = fmaf(sc[rr][k], vv, acc0);
    acc1 = fmaf(sc[rr + 2][k], vv, acc1);
  }
  ws[OFF_OUTSA + (n0 + rr) * CDIM + c]     = acc0 * s_inv[rr];
  ws[OFF_OUTSA + (n0 + rr + 2) * CDIM + c] = acc1 * s_inv[rr + 2];
}

// ---------------------------------------------------------------- da attention
__global__ __launch_bounds__(256) void attn_da_kernel(
    const float* __restrict__ coord, float* __restrict__ ws)
{
  __shared__ float4 qd4[CDIM];
  __shared__ float sc[4][NKV];
  __shared__ float red[4];
  __shared__ float s_inv[4];
  __shared__ float qcr[4][3];
  __shared__ float wd[3];
  int t = threadIdx.x;
  int n0 = blockIdx.x * 4;
  float* qdf = (float*)qd4;
  for (int i = t; i < 4 * CDIM; i += 256) {
    int r = i >> 7, j = i & 127;
    qdf[j * 4 + r] = ws[OFF_QDA + (n0 + r) * CDIM + j];
  }
  if (t < 4) {
    int n = n0 + t;
    float x = (float)(n & 31), y = (float)(n >> 5);
    float u  = (x - 16.5f) * 0.19634954084936207f;  // pi/16
    float vv = (y -  8.5f) * 0.19634954084936207f;
    float cv = cosf(vv);
    qcr[t][0] = cv * sinf(u);
    qcr[t][1] = sinf(vv);
    qcr[t][2] = cv * cosf(u);
  }
  if (t < 3) wd[t] = ws[OFF_WDSUM + t];
  __syncthreads();
  const float* kdat = ws + OFF_KDAT;
  #pragma unroll
  for (int ki = 0; ki < 5; ++ki) {
    int k = t + ki * 256;
    float a0 = 0.f, a1 = 0.f, a2 = 0.f, a3 = 0.f;
    #pragma unroll 4
    for (int j = 0; j < CDIM; ++j) {
      float kv = kdat[j * NKV + k];
      float4 q = qd4[j];
      a0 += __expf(-fabsf(q.x - kv));
      a1 += __expf(-fabsf(q.y - kv));
      a2 += __expf(-fabsf(q.z - kv));
      a3 += __expf(-fabsf(q.w - kv));
    }
    float c0 = coord[k * 3], c1 = coord[k * 3 + 1], c2 = coord[k * 3 + 2];
    float p[4];
    #pragma unroll
    for (int r = 0; r < 4; ++r)
      p[r] = wd[0] * __expf(-fabsf(qcr[r][0] - c0))
           + wd[1] * __expf(-fabsf(qcr[r][1] - c1))
           + wd[2] * __expf(-fabsf(qcr[r][2] - c2));
    sc[0][k] = (a0 + p[0]) * 0.0078125f;  // 1/C
    sc[1][k] = (a1 + p[1]) * 0.0078125f;
    sc[2][k] = (a2 + p[2]) * 0.0078125f;
    sc[3][k] = (a3 + p[3]) * 0.0078125f;
  }
  for (int r = 0; r < 4; ++r) {
    float lm = -1e30f;
    #pragma unroll
    for (int ki = 0; ki < 5; ++ki) lm = fmaxf(lm, sc[r][t + ki * 256]);
    for (int o = 32; o > 0; o >>= 1) lm = fmaxf(lm, __shfl_down(lm, o, 64));
    __syncthreads();
    if ((t & 63) == 0) red[t >> 6] = lm;
    __syncthreads();
    float m = fmaxf(fmaxf(red[0], red[1]), fmaxf(red[2], red[3]));
    float ls = 0.f;
    #pragma unroll
    for (int ki = 0; ki < 5; ++ki) {
      int k = t + ki * 256;
      float e = __expf(sc[r][k] - m);
      sc[r][k] = e;
      ls += e;
    }
    for (int o = 32; o > 0; o >>= 1) ls += __shfl_down(ls, o, 64);
    __syncthreads();
    if ((t & 63) == 0) red[t >> 6] = ls;
    __syncthreads();
    if (t == 0) s_inv[r] = 1.0f / (red[0] + red[1] + red[2] + red[3]);
  }
  __syncthreads();
  const float* v = ws + OFF_VDA;
  int c = t & 127, rr = t >> 7;
  float acc0 = 0.f, acc1 = 0.f;
  #pragma unroll 4
  for (int k = 0; k < NKV; ++k) {
    float vv = v[k * CDIM + c];
    acc0 = fmaf(sc[rr][k], vv, acc0);
    acc1 = fmaf(sc[rr + 2][k], vv, acc1);
  }
  ws[OFF_OUTDA + (n0 + rr) * CDIM + c]     = acc0 * s_inv[rr];
  ws[OFF_OUTDA + (n0 + rr + 2) * CDIM + c] = acc1 * s_inv[rr + 2];
}

// ---------------------------------------------------------------- finalize
// one block per query row i: reinterpret-transpose sa, project both, gate, fuse,
// store NCHW.
__global__ __launch_bounds__(128) void finalize_kernel(
    const float* __restrict__ bsa, const float* __restrict__ bda,
    float* __restrict__ out, float* __restrict__ ws)
{
  __shared__ float sain[CDIM];
  __shared__ float dain[CDIM];
  __shared__ float cat[2 * CDIM];
  int i = blockIdx.x, t = threadIdx.x;
  // sa_in[i][j] = out_sa[(i%4)*128 + j][i/4]   (reference's transpose-reshape)
  sain[t] = ws[OFF_OUTSA + ((i & 3) * 128 + t) * CDIM + (i >> 2)];
  dain[t] = ws[OFF_OUTDA + i * CDIM + t];
  __syncthreads();
  const float* psa = ws + OFF_PROJT_SA;
  const float* pda = ws + OFF_PROJT_DA;
  float asa = bsa[t], ada = bda[t];
  #pragma unroll 4
  for (int j = 0; j < CDIM; ++j) {
    asa = fmaf(sain[j], psa[j * CDIM + t], asa);
    ada = fmaf(dain[j], pda[j * CDIM + t], ada);
  }
  cat[t] = asa;
  cat[CDIM + t] = ada;
  __syncthreads();
  const float* gsa = ws + OFF_GATET_SA;
  const float* gda = ws + OFF_GATET_DA;
  float g1 = 0.f, g2 = 0.f;
  #pragma unroll 4
  for (int j = 0; j < 2 * CDIM; ++j) {
    float cj = cat[j];
    g1 = fmaf(cj, gsa[j * CDIM + t], g1);
    g2 = fmaf(cj, gda[j * CDIM + t], g2);
  }
  g1 = 1.0f / (1.0f + __expf(-g1));
  g2 = 1.0f / (1.0f + __expf(-g2));
  out[t * NQ + i] = g1 * asa + g2 * ada;   // out[c][h][w]
}

// ---------------------------------------------------------------- launch
extern "C" void kernel_launch(void* const* d_in, const int* in_sizes, int n_in,
                              void* d_out, int out_size, void* d_ws, size_t ws_size,
                              hipStream_t stream)
{
  (void)in_sizes; (void)n_in; (void)out_size; (void)ws_size;
  const float* erp       = (const float*)d_in[0];
  const float* ico       = (const float*)d_in[1];
  const float* coord     = (const float*)d_in[2];
  const float* wq_sa     = (const float*)d_in[3];
  const float* wkv_sa    = (const float*)d_in[4];
  const float* proj_sa_w = (const float*)d_in[5];
  const float* proj_sa_b = (const float*)d_in[6];
  const float* wq_da     = (const float*)d_in[7];
  const float* wkv_da    = (const float*)d_in[8];
  const float* wdelta    = (const float*)d_in[9];
  const float* proj_da_w = (const float*)d_in[10];
  const float* proj_da_b = (const float*)d_in[11];
  const float* gate_sa   = (const float*)d_in[12];
  const float* gate_da   = (const float*)d_in[13];
  float* out = (float*)d_out;
  float* ws  = (float*)d_ws;

  hipLaunchKernelGGL(prep_weights_kernel, dim3(321), dim3(256), 0, stream,
                     wq_sa, wkv_sa, proj_sa_w, wq_da, wkv_da, proj_da_w,
                     gate_sa, gate_da, wdelta, ws);
  hipLaunchKernelGGL(qproj_kernel,  dim3(64),  dim3(256), 0, stream, erp, ws);
  hipLaunchKernelGGL(kvproj_kernel, dim3(160), dim3(256), 0, stream, ico, ws);
  hipLaunchKernelGGL(attn_sa_kernel, dim3(128), dim3(256), 0, stream, ws);
  hipLaunchKernelGGL(attn_da_kernel, dim3(128), dim3(256), 0, stream, coord, ws);
  hipLaunchKernelGGL(finalize_kernel, dim3(512), dim3(128), 0, stream,
                     proj_sa_b, proj_da_b, out, ws);
}

// Round 2
// 180.396 us; speedup vs baseline: 2.5067x; 2.5067x over previous
//
#include <hip/hip_runtime.h>
#include <math.h>

#define NQ   512
#define NKV  1280
#define CDIM 128

// workspace layout (float offsets)
#define OFF_WQT_SA   0         // 16384  [j=128][c=128]
#define OFF_WQT_DA   16384     // 16384
#define OFF_WKVT_SA  32768     // 32768  [j=128][c=256]
#define OFF_WKVT_DA  65536     // 32768
#define OFF_PROJT_SA 98304     // 16384  [j=128][c=128]
#define OFF_PROJT_DA 114688    // 16384
#define OFF_GATET_SA 131072    // 32768  [j=256][c=128]
#define OFF_GATET_DA 163840    // 32768
#define OFF_WDSUM    196608    // 4
#define OFF_QSA      196612    // 65536  [n=512][c=128]
#define OFF_QDA      262148    // 65536
#define OFF_KSAT     327684    // 163840 [c=128][k=1280]  (transposed)
#define OFF_VSA      491524    // 163840 [k=1280][c=128]
#define OFF_KDAT     655364    // 163840 [c=128][k=1280]
#define OFF_VDA      819204    // 163840 [k=1280][c=128]
#define OFF_OUTSA    983044    // 65536  [n=512][c=128] (pre-reinterpret)
#define OFF_OUTDA    1048580   // 65536
#define OFF_LOG_SA   1114116   // 655360 [n=512][k=1280]
#define OFF_LOG_DA   1769476   // 655360
// total 2424836 floats = 9.7 MB

// ---------------------------------------------------------------- weights
__global__ __launch_bounds__(256) void prep_weights_kernel(
    const float* __restrict__ wq_sa, const float* __restrict__ wkv_sa,
    const float* __restrict__ proj_sa, const float* __restrict__ wq_da,
    const float* __restrict__ wkv_da, const float* __restrict__ proj_da,
    const float* __restrict__ gate_sa, const float* __restrict__ gate_da,
    const float* __restrict__ wdelta, float* __restrict__ ws)
{
  int idx = blockIdx.x * 256 + threadIdx.x;
  if (idx < 16384) {                    // all 128x128 matrices
    int j = idx >> 7, c = idx & 127;
    int s = c * 128 + j;
    ws[OFF_WQT_SA + idx]   = wq_sa[s];
    ws[OFF_WQT_DA + idx]   = wq_da[s];
    ws[OFF_PROJT_SA + idx] = proj_sa[s];
    ws[OFF_PROJT_DA + idx] = proj_da[s];
  } else if (idx < 49152) {             // kv weights (256x128)
    int i2 = idx - 16384;
    int j = i2 >> 8, c = i2 & 255;
    int s = c * 128 + j;
    ws[OFF_WKVT_SA + i2] = wkv_sa[s];
    ws[OFF_WKVT_DA + i2] = wkv_da[s];
  } else if (idx < 81920) {             // gate weights (128x256)
    int i2 = idx - 49152;
    int j = i2 >> 7, c = i2 & 127;
    int s = c * 256 + j;
    ws[OFF_GATET_SA + i2] = gate_sa[s];
    ws[OFF_GATET_DA + i2] = gate_da[s];
  } else if (idx < 81923) {             // Wdelta.sum(0)
    int t3 = idx - 81920;
    float s = 0.f;
    for (int i = 0; i < 128; ++i) s += wdelta[i * 3 + t3];
    ws[OFF_WDSUM + t3] = s;
  }
}

// ---------------------------------------------------------------- q proj
// block: 256 threads, 4 query rows. t<128 -> q_sa feature t; t>=128 -> q_da.
__global__ __launch_bounds__(256) void qproj_kernel(
    const float* __restrict__ erp, float* __restrict__ ws)
{
  __shared__ float qrows[4][CDIM];
  int n0 = blockIdx.x * 4, t = threadIdx.x;
  for (int i = t; i < 4 * CDIM; i += 256)
    qrows[i & 3][i >> 2] = erp[(i >> 2) * NQ + n0 + (i & 3)];
  __syncthreads();
  const float* w = (t < 128) ? (ws + OFF_WQT_SA) : (ws + OFF_WQT_DA);
  int c = t & 127;
  float acc[4] = {0,0,0,0};
  #pragma unroll 4
  for (int j = 0; j < CDIM; ++j) {
    float wj = w[j * 128 + c];
    #pragma unroll
    for (int r = 0; r < 4; ++r) acc[r] = fmaf(qrows[r][j], wj, acc[r]);
  }
  float* o = (t < 128) ? (ws + OFF_QSA) : (ws + OFF_QDA);
  #pragma unroll
  for (int r = 0; r < 4; ++r) o[(n0 + r) * CDIM + c] = acc[r];
}

// ---------------------------------------------------------------- kv proj
// block: 256 threads, 4 keys. t<128: k feature t ; t>=128: v feature t-128.
__global__ __launch_bounds__(256) void kvproj_kernel(
    const float* __restrict__ ico, float* __restrict__ ws)
{
  __shared__ float irow[4][CDIM];
  int k0 = blockIdx.x * 4, t = threadIdx.x;
  for (int i = t; i < 4 * CDIM; i += 256)
    irow[i >> 7][i & 127] = ico[(k0 + (i >> 7)) * CDIM + (i & 127)];
  __syncthreads();
  const float* wsa = ws + OFF_WKVT_SA;
  const float* wda = ws + OFF_WKVT_DA;
  float acc_s[4] = {0,0,0,0};
  float acc_d[4] = {0,0,0,0};
  #pragma unroll 4
  for (int j = 0; j < CDIM; ++j) {
    float wsj = wsa[j * 256 + t];
    float wdj = wda[j * 256 + t];
    #pragma unroll
    for (int ky = 0; ky < 4; ++ky) {
      float x = irow[ky][j];
      acc_s[ky] = fmaf(x, wsj, acc_s[ky]);
      acc_d[ky] = fmaf(x, wdj, acc_d[ky]);
    }
  }
  if (t < 128) {  // k features -> transposed layout, 4 consecutive k = float4
    *(float4*)(ws + OFF_KSAT + t * NKV + k0) =
        make_float4(acc_s[0], acc_s[1], acc_s[2], acc_s[3]);
    *(float4*)(ws + OFF_KDAT + t * NKV + k0) =
        make_float4(acc_d[0], acc_d[1], acc_d[2], acc_d[3]);
  } else {        // v features -> row-major
    int c = t - 128;
    #pragma unroll
    for (int ky = 0; ky < 4; ++ky) {
      ws[OFF_VSA + (k0 + ky) * CDIM + c] = acc_s[ky];
      ws[OFF_VDA + (k0 + ky) * CDIM + c] = acc_d[ky];
    }
  }
}

// ---------------------------------------------------------------- scores
// grid: (128 q-groups, 2 branches, 5 k-splits). block 256, thread-per-k.
// br 0: sa logits = (q.k) * C^-0.5 ; br 1: da logits = (feat+pos)/C
__global__ __launch_bounds__(256) void score_kernel(
    const float* __restrict__ coord, float* __restrict__ ws)
{
  __shared__ float4 q4[CDIM];           // [j] -> 4 rows
  __shared__ float qcr[4][3];
  __shared__ float wd[3];
  int t = threadIdx.x;
  int n0 = blockIdx.x * 4;
  int br = blockIdx.y;
  int k  = blockIdx.z * 256 + t;
  float* qf = (float*)q4;
  const float* qsrc = ws + (br ? OFF_QDA : OFF_QSA);
  for (int i = t; i < 4 * CDIM; i += 256) {
    int r = i >> 7, j = i & 127;
    qf[j * 4 + r] = qsrc[(n0 + r) * CDIM + j];
  }
  if (br && t < 4) {
    int n = n0 + t;
    float x = (float)(n & 31), y = (float)(n >> 5);
    float u  = (x - 16.5f) * 0.19634954084936207f;  // pi/16
    float vv = (y -  8.5f) * 0.19634954084936207f;
    float cv = cosf(vv);
    qcr[t][0] = cv * sinf(u);
    qcr[t][1] = sinf(vv);
    qcr[t][2] = cv * cosf(u);
  }
  if (br && t < 3) wd[t] = ws[OFF_WDSUM + t];
  __syncthreads();

  float a0, a1, a2, a3;
  if (br == 0) {
    const float* ksat = ws + OFF_KSAT;
    a0 = a1 = a2 = a3 = 0.f;
    #pragma unroll 8
    for (int j = 0; j < CDIM; ++j) {
      float kv = ksat[j * NKV + k];
      float4 q = q4[j];
      a0 = fmaf(q.x, kv, a0);
      a1 = fmaf(q.y, kv, a1);
      a2 = fmaf(q.z, kv, a2);
      a3 = fmaf(q.w, kv, a3);
    }
    const float scale = 0.088388347648318447f;  // 128^-0.5
    float* lg = ws + OFF_LOG_SA;
    lg[(n0 + 0) * NKV + k] = a0 * scale;
    lg[(n0 + 1) * NKV + k] = a1 * scale;
    lg[(n0 + 2) * NKV + k] = a2 * scale;
    lg[(n0 + 3) * NKV + k] = a3 * scale;
  } else {
    const float* kdat = ws + OFF_KDAT;
    a0 = a1 = a2 = a3 = 0.f;
    #pragma unroll 8
    for (int j = 0; j < CDIM; ++j) {
      float kv = kdat[j * NKV + k];
      float4 q = q4[j];
      a0 += __expf(-fabsf(q.x - kv));
      a1 += __expf(-fabsf(q.y - kv));
      a2 += __expf(-fabsf(q.z - kv));
      a3 += __expf(-fabsf(q.w - kv));
    }
    float c0 = coord[k * 3], c1 = coord[k * 3 + 1], c2 = coord[k * 3 + 2];
    float w0 = wd[0], w1 = wd[1], w2 = wd[2];
    float* lg = ws + OFF_LOG_DA;
    #pragma unroll
    for (int r = 0; r < 4; ++r) {
      float p = w0 * __expf(-fabsf(qcr[r][0] - c0))
              + w1 * __expf(-fabsf(qcr[r][1] - c1))
              + w2 * __expf(-fabsf(qcr[r][2] - c2));
      float a = (r == 0) ? a0 : (r == 1) ? a1 : (r == 2) ? a2 : a3;
      lg[(n0 + r) * NKV + k] = (a + p) * 0.0078125f;   // 1/C
    }
  }
}

// ---------------------------------------------------------------- softmax+AV
// grid: (256 q-pairs, 2 branches). block 256. 2 q rows per block.
__global__ __launch_bounds__(256) void softmax_av_kernel(float* __restrict__ ws)
{
  __shared__ float sc[2][NKV];
  __shared__ float red[4];
  __shared__ float inv_s[2];
  __shared__ float part[2][2][CDIM];    // [k-half][row][c]
  int t = threadIdx.x;
  int n0 = blockIdx.x * 2;
  int br = blockIdx.y;
  const float* lg = ws + (br ? OFF_LOG_DA : OFF_LOG_SA);
  #pragma unroll
  for (int r = 0; r < 2; ++r)
    #pragma unroll
    for (int ki = 0; ki < 5; ++ki)
      sc[r][ki * 256 + t] = lg[(n0 + r) * NKV + ki * 256 + t];
  __syncthreads();
  for (int r = 0; r < 2; ++r) {
    float lm = -1e30f;
    #pragma unroll
    for (int ki = 0; ki < 5; ++ki) lm = fmaxf(lm, sc[r][ki * 256 + t]);
    for (int o = 32; o > 0; o >>= 1) lm = fmaxf(lm, __shfl_down(lm, o, 64));
    __syncthreads();
    if ((t & 63) == 0) red[t >> 6] = lm;
    __syncthreads();
    float m = fmaxf(fmaxf(red[0], red[1]), fmaxf(red[2], red[3]));
    float ls = 0.f;
    #pragma unroll
    for (int ki = 0; ki < 5; ++ki) {
      int k = ki * 256 + t;
      float e = __expf(sc[r][k] - m);
      sc[r][k] = e;
      ls += e;
    }
    for (int o = 32; o > 0; o >>= 1) ls += __shfl_down(ls, o, 64);
    __syncthreads();
    if ((t & 63) == 0) red[t >> 6] = ls;
    __syncthreads();
    if (t == 0) inv_s[r] = 1.0f / (red[0] + red[1] + red[2] + red[3]);
    __syncthreads();
  }
  const float* v = ws + (br ? OFF_VDA : OFF_VSA);
  int c = t & 127, half = t >> 7;
  int kb = half * 640;
  float acc0 = 0.f, acc1 = 0.f;
  #pragma unroll 8
  for (int ko = 0; ko < 640; ++ko) {
    int k = kb + ko;
    float vv = v[k * CDIM + c];
    acc0 = fmaf(sc[0][k], vv, acc0);
    acc1 = fmaf(sc[1][k], vv, acc1);
  }
  part[half][0][c] = acc0;
  part[half][1][c] = acc1;
  __syncthreads();
  {
    int r = t >> 7, cc = t & 127;
    float val = (part[0][r][cc] + part[1][r][cc]) * inv_s[r];
    float* o = ws + (br ? OFF_OUTDA : OFF_OUTSA);
    o[(n0 + r) * CDIM + cc] = val;
  }
}

// ---------------------------------------------------------------- finalize
// one block per query row i: reinterpret-transpose sa, project both, gate, fuse,
// store NCHW.
__global__ __launch_bounds__(128) void finalize_kernel(
    const float* __restrict__ bsa, const float* __restrict__ bda,
    float* __restrict__ out, float* __restrict__ ws)
{
  __shared__ float sain[CDIM];
  __shared__ float dain[CDIM];
  __shared__ float cat[2 * CDIM];
  int i = blockIdx.x, t = threadIdx.x;
  // sa_in[i][j] = out_sa[(i%4)*128 + j][i/4]   (reference's transpose-reshape)
  sain[t] = ws[OFF_OUTSA + ((i & 3) * 128 + t) * CDIM + (i >> 2)];
  dain[t] = ws[OFF_OUTDA + i * CDIM + t];
  __syncthreads();
  const float* psa = ws + OFF_PROJT_SA;
  const float* pda = ws + OFF_PROJT_DA;
  float s0=0,s1=0,s2=0,s3=0, d0=0,d1=0,d2=0,d3=0;
  #pragma unroll 4
  for (int j = 0; j < CDIM; j += 4) {
    s0 = fmaf(sain[j],   psa[(j)   * CDIM + t], s0);
    s1 = fmaf(sain[j+1], psa[(j+1) * CDIM + t], s1);
    s2 = fmaf(sain[j+2], psa[(j+2) * CDIM + t], s2);
    s3 = fmaf(sain[j+3], psa[(j+3) * CDIM + t], s3);
    d0 = fmaf(dain[j],   pda[(j)   * CDIM + t], d0);
    d1 = fmaf(dain[j+1], pda[(j+1) * CDIM + t], d1);
    d2 = fmaf(dain[j+2], pda[(j+2) * CDIM + t], d2);
    d3 = fmaf(dain[j+3], pda[(j+3) * CDIM + t], d3);
  }
  float asa = bsa[t] + ((s0 + s1) + (s2 + s3));
  float ada = bda[t] + ((d0 + d1) + (d2 + d3));
  cat[t] = asa;
  cat[CDIM + t] = ada;
  __syncthreads();
  const float* gsa = ws + OFF_GATET_SA;
  const float* gda = ws + OFF_GATET_DA;
  float g10=0,g11=0,g12=0,g13=0, g20=0,g21=0,g22=0,g23=0;
  #pragma unroll 4
  for (int j = 0; j < 2 * CDIM; j += 4) {
    g10 = fmaf(cat[j],   gsa[(j)   * CDIM + t], g10);
    g11 = fmaf(cat[j+1], gsa[(j+1) * CDIM + t], g11);
    g12 = fmaf(cat[j+2], gsa[(j+2) * CDIM + t], g12);
    g13 = fmaf(cat[j+3], gsa[(j+3) * CDIM + t], g13);
    g20 = fmaf(cat[j],   gda[(j)   * CDIM + t], g20);
    g21 = fmaf(cat[j+1], gda[(j+1) * CDIM + t], g21);
    g22 = fmaf(cat[j+2], gda[(j+2) * CDIM + t], g22);
    g23 = fmaf(cat[j+3], gda[(j+3) * CDIM + t], g23);
  }
  float g1 = ((g10 + g11) + (g12 + g13));
  float g2 = ((g20 + g21) + (g22 + g23));
  g1 = 1.0f / (1.0f + __expf(-g1));
  g2 = 1.0f / (1.0f + __expf(-g2));
  out[t * NQ + i] = g1 * asa + g2 * ada;   // out[c][h][w]
}

// ---------------------------------------------------------------- launch
extern "C" void kernel_launch(void* const* d_in, const int* in_sizes, int n_in,
                              void* d_out, int out_size, void* d_ws, size_t ws_size,
                              hipStream_t stream)
{
  (void)in_sizes; (void)n_in; (void)out_size; (void)ws_size;
  const float* erp       = (const float*)d_in[0];
  const float* ico       = (const float*)d_in[1];
  const float* coord     = (const float*)d_in[2];
  const float* wq_sa     = (const float*)d_in[3];
  const float* wkv_sa    = (const float*)d_in[4];
  const float* proj_sa_w = (const float*)d_in[5];
  const float* proj_sa_b = (const float*)d_in[6];
  const float* wq_da     = (const float*)d_in[7];
  const float* wkv_da    = (const float*)d_in[8];
  const float* wdelta    = (const float*)d_in[9];
  const float* proj_da_w = (const float*)d_in[10];
  const float* proj_da_b = (const float*)d_in[11];
  const float* gate_sa   = (const float*)d_in[12];
  const float* gate_da   = (const float*)d_in[13];
  float* out = (float*)d_out;
  float* ws  = (float*)d_ws;

  hipLaunchKernelGGL(prep_weights_kernel, dim3(321), dim3(256), 0, stream,
                     wq_sa, wkv_sa, proj_sa_w, wq_da, wkv_da, proj_da_w,
                     gate_sa, gate_da, wdelta, ws);
  hipLaunchKernelGGL(qproj_kernel,  dim3(128), dim3(256), 0, stream, erp, ws);
  hipLaunchKernelGGL(kvproj_kernel, dim3(320), dim3(256), 0, stream, ico, ws);
  hipLaunchKernelGGL(score_kernel, dim3(128, 2, 5), dim3(256), 0, stream,
                     coord, ws);
  hipLaunchKernelGGL(softmax_av_kernel, dim3(256, 2), dim3(256), 0, stream, ws);
  hipLaunchKernelGGL(finalize_kernel, dim3(512), dim3(128), 0, stream,
                     proj_sa_b, proj_da_b, out, ws);
}

// Round 3
// 173.436 us; speedup vs baseline: 2.6072x; 1.0401x over previous
//
#include <hip/hip_runtime.h>
#include <math.h>

#define NQ   512
#define NKV  1280
#define CDIM 128

// workspace layout (float offsets, all 64B-aligned)
#define OFF_WDSUM  0         // 3
#define OFF_QSA    16        // 65536  [n=512][c=128]
#define OFF_QDA    65552     // 65536
#define OFF_KSAT   131088    // 163840 [c=128][k=1280] (transposed)
#define OFF_VSA    294928    // 163840 [k=1280][c=128]
#define OFF_KDAT   458768    // 163840
#define OFF_VDA    622608    // 163840
#define OFF_OUTSA  786448    // 65536  [n=512][c=128]
#define OFF_OUTDA  851984    // 65536
#define OFF_LOG_SA 917520    // 655360 [n=512][k=1280]
#define OFF_LOG_DA 1572880   // 655360
// total 2228240 floats = 8.9 MB

// ---------------------------------------------------------------- proj
// bx<128: q projection (4 query rows); 128<=bx<448: kv projection (4 keys);
// bx==448: Wdelta.sum(0). Weights read in ORIGINAL layout (row walks, float4).
__global__ __launch_bounds__(256) void proj_kernel(
    const float* __restrict__ erp, const float* __restrict__ ico,
    const float* __restrict__ wq_sa, const float* __restrict__ wq_da,
    const float* __restrict__ wkv_sa, const float* __restrict__ wkv_da,
    const float* __restrict__ wdelta, float* __restrict__ ws)
{
  int bx = blockIdx.x, t = threadIdx.x;
  if (bx < 128) {
    __shared__ float q4[4 * CDIM];          // [j*4 + r]
    int n0 = bx * 4;
    for (int i = t; i < 512; i += 256)
      q4[i] = erp[(i >> 2) * NQ + n0 + (i & 3)];
    __syncthreads();
    const float* w = (t < 128) ? wq_sa : wq_da;
    int c = t & 127;
    const float4* w4 = (const float4*)(w + c * CDIM);
    float a0 = 0.f, a1 = 0.f, a2 = 0.f, a3 = 0.f;
    #pragma unroll 8
    for (int j4 = 0; j4 < 32; ++j4) {
      float4 wv = w4[j4];
      float4 q0 = *(const float4*)&q4[(j4 * 4 + 0) * 4];
      float4 q1 = *(const float4*)&q4[(j4 * 4 + 1) * 4];
      float4 q2 = *(const float4*)&q4[(j4 * 4 + 2) * 4];
      float4 q3 = *(const float4*)&q4[(j4 * 4 + 3) * 4];
      a0 = fmaf(wv.x, q0.x, a0); a1 = fmaf(wv.x, q0.y, a1);
      a2 = fmaf(wv.x, q0.z, a2); a3 = fmaf(wv.x, q0.w, a3);
      a0 = fmaf(wv.y, q1.x, a0); a1 = fmaf(wv.y, q1.y, a1);
      a2 = fmaf(wv.y, q1.z, a2); a3 = fmaf(wv.y, q1.w, a3);
      a0 = fmaf(wv.z, q2.x, a0); a1 = fmaf(wv.z, q2.y, a1);
      a2 = fmaf(wv.z, q2.z, a2); a3 = fmaf(wv.z, q2.w, a3);
      a0 = fmaf(wv.w, q3.x, a0); a1 = fmaf(wv.w, q3.y, a1);
      a2 = fmaf(wv.w, q3.z, a2); a3 = fmaf(wv.w, q3.w, a3);
    }
    float* o = ws + ((t < 128) ? OFF_QSA : OFF_QDA);
    o[(n0 + 0) * CDIM + c] = a0;
    o[(n0 + 1) * CDIM + c] = a1;
    o[(n0 + 2) * CDIM + c] = a2;
    o[(n0 + 3) * CDIM + c] = a3;
  } else if (bx < 448) {
    __shared__ float x4[4 * CDIM];          // [j*4 + ky]
    int k0 = (bx - 128) * 4;
    for (int i = t; i < 512; i += 256) {
      int ky = i >> 7, j = i & 127;
      x4[j * 4 + ky] = ico[(k0 + ky) * CDIM + j];
    }
    __syncthreads();
    const float4* wsa4 = (const float4*)(wkv_sa + t * CDIM);
    const float4* wda4 = (const float4*)(wkv_da + t * CDIM);
    float as0=0,as1=0,as2=0,as3=0, ad0=0,ad1=0,ad2=0,ad3=0;
    #pragma unroll 4
    for (int j4 = 0; j4 < 32; ++j4) {
      float4 wsv = wsa4[j4];
      float4 wdv = wda4[j4];
      float4 x0 = *(const float4*)&x4[(j4 * 4 + 0) * 4];
      float4 x1 = *(const float4*)&x4[(j4 * 4 + 1) * 4];
      float4 x2 = *(const float4*)&x4[(j4 * 4 + 2) * 4];
      float4 x3 = *(const float4*)&x4[(j4 * 4 + 3) * 4];
      as0 = fmaf(wsv.x, x0.x, as0); as1 = fmaf(wsv.x, x0.y, as1);
      as2 = fmaf(wsv.x, x0.z, as2); as3 = fmaf(wsv.x, x0.w, as3);
      ad0 = fmaf(wdv.x, x0.x, ad0); ad1 = fmaf(wdv.x, x0.y, ad1);
      ad2 = fmaf(wdv.x, x0.z, ad2); ad3 = fmaf(wdv.x, x0.w, ad3);
      as0 = fmaf(wsv.y, x1.x, as0); as1 = fmaf(wsv.y, x1.y, as1);
      as2 = fmaf(wsv.y, x1.z, as2); as3 = fmaf(wsv.y, x1.w, as3);
      ad0 = fmaf(wdv.y, x1.x, ad0); ad1 = fmaf(wdv.y, x1.y, ad1);
      ad2 = fmaf(wdv.y, x1.z, ad2); ad3 = fmaf(wdv.y, x1.w, ad3);
      as0 = fmaf(wsv.z, x2.x, as0); as1 = fmaf(wsv.z, x2.y, as1);
      as2 = fmaf(wsv.z, x2.z, as2); as3 = fmaf(wsv.z, x2.w, as3);
      ad0 = fmaf(wdv.z, x2.x, ad0); ad1 = fmaf(wdv.z, x2.y, ad1);
      ad2 = fmaf(wdv.z, x2.z, ad2); ad3 = fmaf(wdv.z, x2.w, ad3);
      as0 = fmaf(wsv.w, x3.x, as0); as1 = fmaf(wsv.w, x3.y, as1);
      as2 = fmaf(wsv.w, x3.z, as2); as3 = fmaf(wsv.w, x3.w, as3);
      ad0 = fmaf(wdv.w, x3.x, ad0); ad1 = fmaf(wdv.w, x3.y, ad1);
      ad2 = fmaf(wdv.w, x3.z, ad2); ad3 = fmaf(wdv.w, x3.w, ad3);
    }
    if (t < 128) {   // k features -> transposed [c][k]
      *(float4*)(ws + OFF_KSAT + t * NKV + k0) = make_float4(as0, as1, as2, as3);
      *(float4*)(ws + OFF_KDAT + t * NKV + k0) = make_float4(ad0, ad1, ad2, ad3);
    } else {         // v features -> [k][c]
      int c = t - 128;
      ws[OFF_VSA + (k0 + 0) * CDIM + c] = as0;
      ws[OFF_VSA + (k0 + 1) * CDIM + c] = as1;
      ws[OFF_VSA + (k0 + 2) * CDIM + c] = as2;
      ws[OFF_VSA + (k0 + 3) * CDIM + c] = as3;
      ws[OFF_VDA + (k0 + 0) * CDIM + c] = ad0;
      ws[OFF_VDA + (k0 + 1) * CDIM + c] = ad1;
      ws[OFF_VDA + (k0 + 2) * CDIM + c] = ad2;
      ws[OFF_VDA + (k0 + 3) * CDIM + c] = ad3;
    }
  } else {
    __shared__ float acc[3];
    if (t < 3) acc[t] = 0.f;
    __syncthreads();
    if (t < 128) {
      atomicAdd(&acc[0], wdelta[t * 3 + 0]);
      atomicAdd(&acc[1], wdelta[t * 3 + 1]);
      atomicAdd(&acc[2], wdelta[t * 3 + 2]);
    }
    __syncthreads();
    if (t < 3) ws[OFF_WDSUM + t] = acc[t];
  }
}

// ---------------------------------------------------------------- scores
// grid: (128 q-groups, 2 branches, 5 k-splits). block 256, thread-per-k.
__global__ __launch_bounds__(256) void score_kernel(
    const float* __restrict__ coord, float* __restrict__ ws)
{
  __shared__ float4 q4[CDIM];           // [j] -> 4 rows
  __shared__ float qcr[4][3];
  __shared__ float wd[3];
  int t = threadIdx.x;
  int n0 = blockIdx.x * 4;
  int br = blockIdx.y;
  int k  = blockIdx.z * 256 + t;
  float* qf = (float*)q4;
  const float* qsrc = ws + (br ? OFF_QDA : OFF_QSA);
  for (int i = t; i < 4 * CDIM; i += 256) {
    int r = i >> 7, j = i & 127;
    qf[j * 4 + r] = qsrc[(n0 + r) * CDIM + j];
  }
  if (br && t < 4) {
    int n = n0 + t;
    float x = (float)(n & 31), y = (float)(n >> 5);
    float u  = (x - 16.5f) * 0.19634954084936207f;  // pi/16
    float vv = (y -  8.5f) * 0.19634954084936207f;
    float cv = cosf(vv);
    qcr[t][0] = cv * sinf(u);
    qcr[t][1] = sinf(vv);
    qcr[t][2] = cv * cosf(u);
  }
  if (br && t < 3) wd[t] = ws[OFF_WDSUM + t];
  __syncthreads();

  if (br == 0) {
    const float* ksat = ws + OFF_KSAT;
    float a0 = 0.f, a1 = 0.f, a2 = 0.f, a3 = 0.f;
    #pragma unroll 8
    for (int j = 0; j < CDIM; ++j) {
      float kv = ksat[j * NKV + k];
      float4 q = q4[j];
      a0 = fmaf(q.x, kv, a0);
      a1 = fmaf(q.y, kv, a1);
      a2 = fmaf(q.z, kv, a2);
      a3 = fmaf(q.w, kv, a3);
    }
    const float scale = 0.088388347648318447f;  // 128^-0.5
    float* lg = ws + OFF_LOG_SA;
    lg[(n0 + 0) * NKV + k] = a0 * scale;
    lg[(n0 + 1) * NKV + k] = a1 * scale;
    lg[(n0 + 2) * NKV + k] = a2 * scale;
    lg[(n0 + 3) * NKV + k] = a3 * scale;
  } else {
    float c0 = coord[k * 3], c1 = coord[k * 3 + 1], c2 = coord[k * 3 + 2];
    const float* kdat = ws + OFF_KDAT;
    float a0 = 0.f, a1 = 0.f, a2 = 0.f, a3 = 0.f;
    #pragma unroll 8
    for (int j = 0; j < CDIM; ++j) {
      float kv = kdat[j * NKV + k];
      float4 q = q4[j];
      a0 += __expf(-fabsf(q.x - kv));
      a1 += __expf(-fabsf(q.y - kv));
      a2 += __expf(-fabsf(q.z - kv));
      a3 += __expf(-fabsf(q.w - kv));
    }
    float w0 = wd[0], w1 = wd[1], w2 = wd[2];
    float* lg = ws + OFF_LOG_DA;
    #pragma unroll
    for (int r = 0; r < 4; ++r) {
      float p = w0 * __expf(-fabsf(qcr[r][0] - c0))
              + w1 * __expf(-fabsf(qcr[r][1] - c1))
              + w2 * __expf(-fabsf(qcr[r][2] - c2));
      float a = (r == 0) ? a0 : (r == 1) ? a1 : (r == 2) ? a2 : a3;
      lg[(n0 + r) * NKV + k] = (a + p) * 0.0078125f;   // 1/C
    }
  }
}

// ---------------------------------------------------------------- softmax+AV
// grid: (256 q-pairs, 2 branches). block 256: softmax from registers, AV with
// 4-way k-split, float2 V loads, float4 broadcast P reads.
__global__ __launch_bounds__(256) void softmax_av_kernel(float* __restrict__ ws)
{
  __shared__ float sc[2][NKV];
  __shared__ float red[8];
  __shared__ float part[4][2][CDIM];
  int t = threadIdx.x;
  int n0 = blockIdx.x * 2;
  int br = blockIdx.y;
  const float* lg = ws + (br ? OFF_LOG_DA : OFF_LOG_SA);
  float v0[5], v1[5];
  float lm0 = -1e30f, lm1 = -1e30f;
  #pragma unroll
  for (int ki = 0; ki < 5; ++ki) {
    v0[ki] = lg[(n0 + 0) * NKV + ki * 256 + t];
    v1[ki] = lg[(n0 + 1) * NKV + ki * 256 + t];
    lm0 = fmaxf(lm0, v0[ki]);
    lm1 = fmaxf(lm1, v1[ki]);
  }
  for (int o = 32; o > 0; o >>= 1) {
    lm0 = fmaxf(lm0, __shfl_down(lm0, o, 64));
    lm1 = fmaxf(lm1, __shfl_down(lm1, o, 64));
  }
  if ((t & 63) == 0) { red[t >> 6] = lm0; red[4 + (t >> 6)] = lm1; }
  __syncthreads();
  float m0 = fmaxf(fmaxf(red[0], red[1]), fmaxf(red[2], red[3]));
  float m1 = fmaxf(fmaxf(red[4], red[5]), fmaxf(red[6], red[7]));
  float s0 = 0.f, s1 = 0.f;
  #pragma unroll
  for (int ki = 0; ki < 5; ++ki) {
    float e0 = __expf(v0[ki] - m0);
    float e1 = __expf(v1[ki] - m1);
    sc[0][ki * 256 + t] = e0;
    sc[1][ki * 256 + t] = e1;
    s0 += e0; s1 += e1;
  }
  for (int o = 32; o > 0; o >>= 1) {
    s0 += __shfl_down(s0, o, 64);
    s1 += __shfl_down(s1, o, 64);
  }
  __syncthreads();   // also covers sc[] visibility before AV reads
  if ((t & 63) == 0) { red[t >> 6] = s0; red[4 + (t >> 6)] = s1; }
  __syncthreads();
  float is0 = 1.0f / (red[0] + red[1] + red[2] + red[3]);
  float is1 = 1.0f / (red[4] + red[5] + red[6] + red[7]);

  const float* v = ws + (br ? OFF_VDA : OFF_VSA);
  int quarter = t >> 6;
  int c0 = (t & 63) * 2;
  int kb = quarter * 320;
  float a00 = 0.f, a01 = 0.f, a10 = 0.f, a11 = 0.f;
  #pragma unroll 2
  for (int ko = 0; ko < 320; ko += 4) {
    int k = kb + ko;
    float4 p0 = *(const float4*)&sc[0][k];
    float4 p1 = *(const float4*)&sc[1][k];
    float2 va = *(const float2*)&v[(k + 0) * CDIM + c0];
    float2 vb = *(const float2*)&v[(k + 1) * CDIM + c0];
    float2 vc = *(const float2*)&v[(k + 2) * CDIM + c0];
    float2 vd = *(const float2*)&v[(k + 3) * CDIM + c0];
    a00 = fmaf(p0.x, va.x, a00); a01 = fmaf(p0.x, va.y, a01);
    a10 = fmaf(p1.x, va.x, a10); a11 = fmaf(p1.x, va.y, a11);
    a00 = fmaf(p0.y, vb.x, a00); a01 = fmaf(p0.y, vb.y, a01);
    a10 = fmaf(p1.y, vb.x, a10); a11 = fmaf(p1.y, vb.y, a11);
    a00 = fmaf(p0.z, vc.x, a00); a01 = fmaf(p0.z, vc.y, a01);
    a10 = fmaf(p1.z, vc.x, a10); a11 = fmaf(p1.z, vc.y, a11);
    a00 = fmaf(p0.w, vd.x, a00); a01 = fmaf(p0.w, vd.y, a01);
    a10 = fmaf(p1.w, vd.x, a10); a11 = fmaf(p1.w, vd.y, a11);
  }
  part[quarter][0][c0] = a00; part[quarter][0][c0 + 1] = a01;
  part[quarter][1][c0] = a10; part[quarter][1][c0 + 1] = a11;
  __syncthreads();
  {
    int r = t >> 7, c = t & 127;
    float sum = part[0][r][c] + part[1][r][c] + part[2][r][c] + part[3][r][c];
    float* o = ws + (br ? OFF_OUTDA : OFF_OUTSA);
    o[(n0 + r) * CDIM + c] = sum * (r ? is1 : is0);
  }
}

// ---------------------------------------------------------------- finalize
// one block per query row: reinterpret-transpose sa, project, gate, fuse, NCHW.
// weights read in original layout (per-thread float4 row walks).
__global__ __launch_bounds__(128) void finalize_kernel(
    const float* __restrict__ psa, const float* __restrict__ bsa,
    const float* __restrict__ pda, const float* __restrict__ bda,
    const float* __restrict__ gsa, const float* __restrict__ gda,
    float* __restrict__ out, float* __restrict__ ws)
{
  __shared__ float sain[CDIM];
  __shared__ float dain[CDIM];
  __shared__ float cat[2 * CDIM];
  int i = blockIdx.x, t = threadIdx.x;
  // sa_in[i][j] = out_sa[(i%4)*128 + j][i/4]   (reference's transpose-reshape)
  sain[t] = ws[OFF_OUTSA + ((i & 3) * 128 + t) * CDIM + (i >> 2)];
  dain[t] = ws[OFF_OUTDA + i * CDIM + t];
  __syncthreads();
  const float4* p4 = (const float4*)(psa + t * CDIM);
  const float4* d4 = (const float4*)(pda + t * CDIM);
  float s0=0,s1=0,s2=0,s3=0, e0=0,e1=0,e2=0,e3=0;
  #pragma unroll 8
  for (int j4 = 0; j4 < 32; ++j4) {
    float4 wv = p4[j4];
    float4 xv = *(const float4*)&sain[j4 * 4];
    s0 = fmaf(wv.x, xv.x, s0); s1 = fmaf(wv.y, xv.y, s1);
    s2 = fmaf(wv.z, xv.z, s2); s3 = fmaf(wv.w, xv.w, s3);
    float4 wv2 = d4[j4];
    float4 yv = *(const float4*)&dain[j4 * 4];
    e0 = fmaf(wv2.x, yv.x, e0); e1 = fmaf(wv2.y, yv.y, e1);
    e2 = fmaf(wv2.z, yv.z, e2); e3 = fmaf(wv2.w, yv.w, e3);
  }
  float asa = bsa[t] + ((s0 + s1) + (s2 + s3));
  float ada = bda[t] + ((e0 + e1) + (e2 + e3));
  cat[t] = asa;
  cat[CDIM + t] = ada;
  __syncthreads();
  const float4* g14 = (const float4*)(gsa + t * 2 * CDIM);
  const float4* g24 = (const float4*)(gda + t * 2 * CDIM);
  float u0=0,u1=0,u2=0,u3=0, w0=0,w1=0,w2=0,w3=0;
  #pragma unroll 8
  for (int j4 = 0; j4 < 64; ++j4) {
    float4 gv = g14[j4];
    float4 cv = *(const float4*)&cat[j4 * 4];
    u0 = fmaf(gv.x, cv.x, u0); u1 = fmaf(gv.y, cv.y, u1);
    u2 = fmaf(gv.z, cv.z, u2); u3 = fmaf(gv.w, cv.w, u3);
    float4 gv2 = g24[j4];
    w0 = fmaf(gv2.x, cv.x, w0); w1 = fmaf(gv2.y, cv.y, w1);
    w2 = fmaf(gv2.z, cv.z, w2); w3 = fmaf(gv2.w, cv.w, w3);
  }
  float g1 = 1.0f / (1.0f + __expf(-((u0 + u1) + (u2 + u3))));
  float g2 = 1.0f / (1.0f + __expf(-((w0 + w1) + (w2 + w3))));
  out[t * NQ + i] = g1 * asa + g2 * ada;   // out[c][h][w]
}

// ---------------------------------------------------------------- launch
extern "C" void kernel_launch(void* const* d_in, const int* in_sizes, int n_in,
                              void* d_out, int out_size, void* d_ws, size_t ws_size,
                              hipStream_t stream)
{
  (void)in_sizes; (void)n_in; (void)out_size; (void)ws_size;
  const float* erp       = (const float*)d_in[0];
  const float* ico       = (const float*)d_in[1];
  const float* coord     = (const float*)d_in[2];
  const float* wq_sa     = (const float*)d_in[3];
  const float* wkv_sa    = (const float*)d_in[4];
  const float* proj_sa_w = (const float*)d_in[5];
  const float* proj_sa_b = (const float*)d_in[6];
  const float* wq_da     = (const float*)d_in[7];
  const float* wkv_da    = (const float*)d_in[8];
  const float* wdelta    = (const float*)d_in[9];
  const float* proj_da_w = (const float*)d_in[10];
  const float* proj_da_b = (const float*)d_in[11];
  const float* gate_sa   = (const float*)d_in[12];
  const float* gate_da   = (const float*)d_in[13];
  float* out = (float*)d_out;
  float* ws  = (float*)d_ws;

  hipLaunchKernelGGL(proj_kernel, dim3(449), dim3(256), 0, stream,
                     erp, ico, wq_sa, wq_da, wkv_sa, wkv_da, wdelta, ws);
  hipLaunchKernelGGL(score_kernel, dim3(128, 2, 5), dim3(256), 0, stream,
                     coord, ws);
  hipLaunchKernelGGL(softmax_av_kernel, dim3(256, 2), dim3(256), 0, stream, ws);
  hipLaunchKernelGGL(finalize_kernel, dim3(512), dim3(128), 0, stream,
                     proj_sa_w, proj_sa_b, proj_da_w, proj_da_b,
                     gate_sa, gate_da, out, ws);
}